// Round 23
// baseline (356.884 us; speedup 1.0000x reference)
//
#include <hip/hip_runtime.h>
#include <cstdint>
#include <cstddef>

constexpr int kN   = 50000;          // nodes
constexpr int kE   = 800000;         // edges (without self loops)
constexpr int kEt  = kE + kN;        // edges + self loops
constexpr float kSlope = 0.2f;       // leaky relu slope
constexpr int kScanB = (kN + 255) / 256;       // 196 scan blocks
constexpr int kConvB = (kN * 16 + 255) / 256;  // x-conversion blocks (3125)
constexpr int kHistB = (kEt + 255) / 256;      // hist blocks (3321)

typedef __attribute__((ext_vector_type(8))) short bf8_t;   // 8 bf16 = 4 VGPRs
typedef __attribute__((ext_vector_type(4))) float f4_t;

// ---------------- static device workspace (d_ws unused) ---------------------
__device__ __align__(16) unsigned short g_xb[(size_t)kN * 128];     // x in bf16
__device__ __align__(16) unsigned short g_aggx[(size_t)kN * 512];   // agg of x, bf16
__device__ __align__(16) unsigned short g_w1t[4 * 128 * 128];       // W1^T per head, bf16
__device__ __align__(16) float g_u[3][512];     // W2 @ [a2s, a2d, fcw]
__device__ __align__(16) float g_es1[kN * 4];
__device__ __align__(16) float g_ed1[kN * 4];
__device__ __align__(16) float2 g_sp[kN];       // {es2, phi} packed
__device__ float g_ed2[kN];
__device__ float g_c0;                          // b2 . fcw + fcb
__device__ __align__(16) float g_p1s[4 * 128];  // folded W1_h @ a1_src_h
__device__ __align__(16) float g_p1d[4 * 128];
// CSR by destination:
__device__ int g_deg[kN];   // starts zero (.bss); re-zeroed by k_scanA each call
__device__ int g_ptr[kN + 1];
__device__ int g_cur[kN];
__device__ int g_srcs[kEt];
__device__ int g_bsum[kScanB];

__device__ __forceinline__ float lrelu(float x) { return x > 0.f ? x : kSlope * x; }

__device__ __forceinline__ bf8_t bf8_zero() {
  uint4 z = make_uint4(0u, 0u, 0u, 0u);
  return *(bf8_t*)&z;
}

// round-to-nearest-even f32 -> bf16
__device__ __forceinline__ unsigned short f2bf1(float v) {
  unsigned u = __float_as_uint(v);
  unsigned r = (u + 0x7FFFu + ((u >> 16) & 1u)) >> 16;
  return (unsigned short)r;
}

// ------- merged init: zero(sp,ed2) | W1 conv | prep1 | U | c0 | hist --------
// g_deg is NOT zeroed here: k_scanA zeroes it after consumption each call,
// so it is always zero at entry (module load zero-inits it for call #1).
__global__ __launch_bounds__(256) void k_init(const int* __restrict__ ei,
    const float* __restrict__ W1, const float* __restrict__ W2,
    const float* __restrict__ a1s, const float* __restrict__ a1d,
    const float* __restrict__ a2s, const float* __restrict__ a2d,
    const float* __restrict__ b2, const float* __restrict__ fcw,
    const float* __restrict__ fcb) {
  const int b = blockIdx.x, t = threadIdx.x;
  if (b < 197) {
    int i = b * 256 + t;
    if (i < kN) {
      g_sp[i] = make_float2(0.f, 0.f);
      g_ed2[i] = 0.f;
    }
  } else if (b < 453) {
    int gid = (b - 197) * 256 + t;   // 0..65535 : W1 -> per-head W1^T bf16
    int h = gid >> 14, rem = gid & 16383;
    int c = rem >> 7, j = rem & 127;
    float v = W1[(size_t)c * 512 + h * 128 + j];
    g_w1t[((size_t)h * 128 + j) * 128 + c] = f2bf1(v);
  } else if (b < 457) {
    int gid = (b - 453) * 256 + t;   // 0..1023 : fold a1 through W1
    int which = gid >> 9, idx = gid & 511;
    int h = idx >> 7, k = idx & 127;
    const float* a = which ? a1d : a1s;
    const float* wrow = W1 + (size_t)k * 512 + h * 128;
    float s = 0.f;
#pragma unroll 8
    for (int c = 0; c < 128; ++c) s += wrow[c] * a[h * 128 + c];
    (which ? g_p1d : g_p1s)[idx] = s;
  } else if (b < 463) {
    int gid = (b - 457) * 256 + t;   // 0..1535 : U[v][k] = W2[k,:] . V_v
    if (gid < 1536) {
      int v = gid >> 9, k = gid & 511;
      const float* vv = v == 0 ? a2s : v == 1 ? a2d : fcw;
      const float* wrow = W2 + (size_t)k * 128;
      float s = 0.f;
#pragma unroll 8
      for (int c = 0; c < 128; ++c) s += wrow[c] * vv[c];
      g_u[v][k] = s;
    }
  } else if (b < 464) {
    if (t < 64) {
      float s = b2[t] * fcw[t] + b2[64 + t] * fcw[64 + t];
#pragma unroll
      for (int off = 32; off > 0; off >>= 1) s += __shfl_down(s, off);
      if (t == 0) g_c0 = s + fcb[0];
    }
  } else {
    // histogram of destination degrees
    int e = (b - 464) * 256 + t;
    if (e < kEt) {
      int d = (e < kE) ? ei[kE + e] : e - kE;
      atomicAdd(&g_deg[d], 1);
    }
  }
}

// ---- x -> bf16 conversion (independent; runs on side stream) ---------------
__global__ __launch_bounds__(256) void k_xconv(const float* __restrict__ x) {
  int g = blockIdx.x * 256 + threadIdx.x;
  if (g >= kN * 16) return;
  const float* xp = x + (size_t)g * 8;
  float4 f0 = *(const float4*)xp;
  float4 f1 = *(const float4*)(xp + 4);
  unsigned w0 = (unsigned)f2bf1(f0.x) | ((unsigned)f2bf1(f0.y) << 16);
  unsigned w1 = (unsigned)f2bf1(f0.z) | ((unsigned)f2bf1(f0.w) << 16);
  unsigned w2 = (unsigned)f2bf1(f1.x) | ((unsigned)f2bf1(f1.y) << 16);
  unsigned w3 = (unsigned)f2bf1(f1.z) | ((unsigned)f2bf1(f1.w) << 16);
  *(uint4*)(g_xb + (size_t)g * 8) = make_uint4(w0, w1, w2, w3);
}

// ---- parallel scan, phase A: per-256-chunk LDS scan + block sums -----------
// Also re-zeroes g_deg after reading (invariant: deg==0 at next call's entry).
__global__ __launch_bounds__(256) void k_scanA() {
  __shared__ int s[256];
  const int b = blockIdx.x, t = threadIdx.x;
  const int i = b * 256 + t;
  int d = (i < kN) ? g_deg[i] : 0;
  s[t] = d;
  __syncthreads();
  for (int off = 1; off < 256; off <<= 1) {
    int v = s[t];
    int u = (t >= off) ? s[t - off] : 0;
    __syncthreads();
    s[t] = v + u;
    __syncthreads();
  }
  if (t == 255) g_bsum[b] = s[255];
  if (i < kN) {
    g_ptr[i] = s[t] - d;   // local exclusive
    g_deg[i] = 0;          // restore invariant for next call
  }
}

// ---- phase C (merged B): every block scans bsum in LDS, adds its offset ----
__global__ __launch_bounds__(256) void k_scanC() {
  __shared__ int s[256];
  const int b = blockIdx.x, t = threadIdx.x;
  int v = (t < kScanB) ? g_bsum[t] : 0;
  s[t] = v;
  __syncthreads();
  for (int off = 1; off < 256; off <<= 1) {
    int a = s[t];
    int u = (t >= off) ? s[t - off] : 0;
    __syncthreads();
    s[t] = a + u;
    __syncthreads();
  }
  const int boff = (b > 0) ? s[b - 1] : 0;   // exclusive offset for this block
  __syncthreads();
  const int i = b * 256 + t;
  if (i < kN) {
    int p = g_ptr[i] + boff;
    g_ptr[i] = p;
    g_cur[i] = p;
  }
  if (b == 0 && t == 0) g_ptr[kN] = kEt;
}

__global__ __launch_bounds__(256) void k_scatter(const int* __restrict__ ei) {
  int e = blockIdx.x * 256 + threadIdx.x;
  if (e >= kEt) return;
  int s, d;
  if (e < kE) { s = ei[e]; d = ei[kE + e]; } else { s = d = e - kE; }
  int slot = atomicAdd(&g_cur[d], 1);
  g_srcs[slot] = s;
}

// ---- layer-1 scores directly from x (side stream, overlaps CSR chain) ------
__global__ __launch_bounds__(256) void k_scores1x(const float* __restrict__ x) {
  const int lane = threadIdx.x & 63;
  const int n = (blockIdx.x * 256 + threadIdx.x) >> 6;
  if (n >= kN) return;
  float x0 = x[(size_t)n * 128 + lane];
  float x1 = x[(size_t)n * 128 + 64 + lane];
  float s[4], d[4];
#pragma unroll
  for (int h = 0; h < 4; ++h) {
    s[h] = x0 * g_p1s[h * 128 + lane] + x1 * g_p1s[h * 128 + 64 + lane];
    d[h] = x0 * g_p1d[h * 128 + lane] + x1 * g_p1d[h * 128 + 64 + lane];
  }
#pragma unroll
  for (int off = 32; off > 0; off >>= 1) {
#pragma unroll
    for (int h = 0; h < 4; ++h) {
      s[h] += __shfl_down(s[h], off);
      d[h] += __shfl_down(d[h], off);
    }
  }
  if (lane == 0) {
    *(float4*)(g_es1 + (size_t)n * 4) = make_float4(s[0], s[1], s[2], s[3]);
    *(float4*)(g_ed1 + (size_t)n * 4) = make_float4(d[0], d[1], d[2], d[3]);
  }
}

// ---- layer-1 aggregation: 4 edges/iter (16-lane quarters), bf16 x gathers --
__global__ __launch_bounds__(256) void k_agg1x() {
  const int lane = threadIdx.x & 63;
  const int n = (blockIdx.x * 256 + threadIdx.x) >> 6;
  if (n >= kN) return;
  const int beg = g_ptr[n], end = g_ptr[n + 1];
  const float4 ed = *(const float4*)(g_ed1 + (size_t)n * 4);
  const int qt = lane >> 4, ql = lane & 15;
  float z0 = 0.f, z1 = 0.f, z2 = 0.f, z3 = 0.f;
  float acc[4][8] = {};
  for (int base = beg; base < end; base += 64) {
    const int cnt = min(64, end - base);
    int s = 0;
    float w0 = 0.f, w1 = 0.f, w2 = 0.f, w3 = 0.f;
    if (lane < cnt) {
      s = g_srcs[base + lane];
      float4 es = *(const float4*)(g_es1 + (size_t)s * 4);
      w0 = __expf(lrelu(es.x + ed.x));
      w1 = __expf(lrelu(es.y + ed.y));
      w2 = __expf(lrelu(es.z + ed.z));
      w3 = __expf(lrelu(es.w + ed.w));
      z0 += w0; z1 += w1; z2 += w2; z3 += w3;
    }
    const int quads = (cnt + 3) >> 2;
#pragma unroll 2
    for (int p = 0; p < quads; ++p) {
      int ei = 4 * p + qt;
      int   sj = __shfl(s, ei);
      float b0 = __shfl(w0, ei), b1 = __shfl(w1, ei);
      float b2 = __shfl(w2, ei), b3 = __shfl(w3, ei);
      uint4 uu = *(const uint4*)(g_xb + (size_t)sj * 128 + ql * 8);
      unsigned ww[4] = {uu.x, uu.y, uu.z, uu.w};
      float fv[8];
#pragma unroll
      for (int wdi = 0; wdi < 4; ++wdi) {
        fv[2 * wdi]     = __uint_as_float(ww[wdi] << 16);
        fv[2 * wdi + 1] = __uint_as_float(ww[wdi] & 0xFFFF0000u);
      }
#pragma unroll
      for (int k = 0; k < 8; ++k) {
        acc[0][k] += b0 * fv[k];
        acc[1][k] += b1 * fv[k];
        acc[2][k] += b2 * fv[k];
        acc[3][k] += b3 * fv[k];
      }
    }
  }
#pragma unroll
  for (int h = 0; h < 4; ++h)
#pragma unroll
    for (int k = 0; k < 8; ++k) {
      acc[h][k] += __shfl_xor(acc[h][k], 16);
      acc[h][k] += __shfl_xor(acc[h][k], 32);
    }
#pragma unroll
  for (int off = 1; off < 64; off <<= 1) {
    z0 += __shfl_xor(z0, off); z1 += __shfl_xor(z1, off);
    z2 += __shfl_xor(z2, off); z3 += __shfl_xor(z3, off);
  }
  float zh = qt == 0 ? z0 : qt == 1 ? z1 : qt == 2 ? z2 : z3;
  float iz = 1.f / zh;
  ushort4 o0, o1;
  float v[8];
#pragma unroll
  for (int k = 0; k < 8; ++k)
    v[k] = (qt == 0 ? acc[0][k] : qt == 1 ? acc[1][k] : qt == 2 ? acc[2][k] : acc[3][k]) * iz;
  o0.x = f2bf1(v[0]); o0.y = f2bf1(v[1]); o0.z = f2bf1(v[2]); o0.w = f2bf1(v[3]);
  o1.x = f2bf1(v[4]); o1.y = f2bf1(v[5]); o1.z = f2bf1(v[6]); o1.w = f2bf1(v[7]);
  size_t o = (size_t)n * 512 + qt * 128 + ql * 8;
  *(ushort4*)(g_aggx + o)     = o0;
  *(ushort4*)(g_aggx + o + 4) = o1;
}

// ------- fused layer-1 expand + layer-2 projections, head-split -------------
__global__ __launch_bounds__(256) void k_fused(const float* __restrict__ b1) {
  __shared__ float sred[2][64][3];
  const int t = threadIdx.x;
  const int lane = t & 63, w = t >> 6;
  const int wrow = w >> 1, wcol = w & 1;
  const int ln15 = lane & 15, q = lane >> 4, qo = q * 8;
  const int row0 = blockIdx.y * 64;
  const int h = blockIdx.z;

  float part[2][4][3] = {};      // [i][reg][v]
  f4_t h1acc[2][4] = {};
#pragma unroll
  for (int ks = 0; ks < 128; ks += 32) {
    bf8_t ah[2];
#pragma unroll
    for (int i = 0; i < 2; ++i) {
      int r = row0 + wrow * 32 + i * 16 + ln15;
      ah[i] = bf8_zero();
      if (r < kN)
        ah[i] = *(const bf8_t*)&g_aggx[(size_t)r * 512 + h * 128 + ks + qo];
    }
#pragma unroll
    for (int j = 0; j < 4; ++j) {
      size_t gb = ((size_t)h * 128 + wcol * 64 + j * 16 + ln15) * 128 + ks + qo;
      bf8_t bh = *(const bf8_t*)&g_w1t[gb];
#pragma unroll
      for (int i = 0; i < 2; ++i)
        h1acc[i][j] = __builtin_amdgcn_mfma_f32_16x16x32_bf16(ah[i], bh, h1acc[i][j], 0, 0, 0);
    }
  }
  // epilogue: relu(h1+b1) dotted with U columns
#pragma unroll
  for (int j = 0; j < 4; ++j) {
    int col = h * 128 + wcol * 64 + j * 16 + ln15;
    float bv = b1[col];
    float u0 = g_u[0][col], u1 = g_u[1][col], u2 = g_u[2][col];
#pragma unroll
    for (int i = 0; i < 2; ++i)
#pragma unroll
      for (int reg = 0; reg < 4; ++reg) {
        float v = fmaxf(h1acc[i][j][reg] + bv, 0.f);
        part[i][reg][0] += v * u0;
        part[i][reg][1] += v * u1;
        part[i][reg][2] += v * u2;
      }
  }
  // reduce over the 16 lanes of each quad-group (same q)
#pragma unroll
  for (int off = 1; off < 16; off <<= 1)
#pragma unroll
    for (int i = 0; i < 2; ++i)
#pragma unroll
      for (int reg = 0; reg < 4; ++reg)
#pragma unroll
        for (int v = 0; v < 3; ++v)
          part[i][reg][v] += __shfl_xor(part[i][reg][v], off);
  if (ln15 == 0) {
#pragma unroll
    for (int i = 0; i < 2; ++i)
#pragma unroll
      for (int reg = 0; reg < 4; ++reg) {
        int rl = wrow * 32 + i * 16 + q * 4 + reg;
#pragma unroll
        for (int v = 0; v < 3; ++v) sred[wcol][rl][v] = part[i][reg][v];
      }
  }
  __syncthreads();
  if (t < 192) {
    int row = t / 3, v = t - row * 3;
    float s = sred[0][row][v] + sred[1][row][v];
    int r = row0 + row;
    if (r < kN) {
      float* dst = v == 0 ? &g_sp[r].x : v == 1 ? &g_ed2[r] : &g_sp[r].y;
      atomicAdd(dst, s);
    }
  }
}

// ---- layer-2 scalar aggregation + output: out = (sum w*phi)/z + c0 ---------
__global__ __launch_bounds__(256) void k_agg2s(float* __restrict__ out) {
  const int lane = threadIdx.x & 63;
  const int n = (blockIdx.x * 256 + threadIdx.x) >> 6;
  if (n >= kN) return;
  const int beg = g_ptr[n], end = g_ptr[n + 1];
  const float ed = g_ed2[n];
  float zp = 0.f, num = 0.f;
  for (int base = beg; base < end; base += 64) {
    int slot = base + lane;
    if (slot < end) {
      int s = g_srcs[slot];
      float2 sp = g_sp[s];
      float w = __expf(lrelu(sp.x + ed));
      zp += w;
      num += w * sp.y;
    }
  }
#pragma unroll
  for (int off = 1; off < 64; off <<= 1) {
    zp  += __shfl_xor(zp, off);
    num += __shfl_xor(num, off);
  }
  if (lane == 0) out[n] = num / zp + g_c0;
}

extern "C" void kernel_launch(void* const* d_in, const int* in_sizes, int n_in,
                              void* d_out, int out_size, void* d_ws, size_t ws_size,
                              hipStream_t stream) {
  const float* x   = (const float*)d_in[0];
  const int*   ei  = (const int*)d_in[1];
  const float* W1  = (const float*)d_in[2];
  const float* a1s = (const float*)d_in[3];
  const float* a1d = (const float*)d_in[4];
  const float* b1  = (const float*)d_in[5];
  const float* W2  = (const float*)d_in[6];
  const float* a2s = (const float*)d_in[7];
  const float* a2d = (const float*)d_in[8];
  const float* b2  = (const float*)d_in[9];
  const float* fcw = (const float*)d_in[10];
  const float* fcb = (const float*)d_in[11];
  float* out = (float*)d_out;
  (void)d_ws; (void)ws_size; (void)in_sizes; (void)n_in; (void)out_size;

  // Lazily created once (during the uncaptured correctness call); the
  // captured call performs the identical record/wait/launch sequence.
  static hipStream_t s2 = nullptr;
  static hipEvent_t e0 = nullptr, e1 = nullptr, e2 = nullptr;
  if (s2 == nullptr) {
    hipStreamCreateWithFlags(&s2, hipStreamNonBlocking);
    hipEventCreateWithFlags(&e0, hipEventDisableTiming);
    hipEventCreateWithFlags(&e1, hipEventDisableTiming);
    hipEventCreateWithFlags(&e2, hipEventDisableTiming);
  }

  // fork side stream from main
  hipEventRecord(e0, stream);
  hipStreamWaitEvent(s2, e0, 0);

  // side: x -> bf16 (no deps) ; main: init (+hist)
  k_xconv<<<kConvB, 256, 0, s2>>>(x);
  k_init<<<464 + kHistB, 256, 0, stream>>>(ei, W1, W2, a1s, a1d, a2s, a2d, b2, fcw, fcb);

  // side waits for init (needs p1s/p1d), then scores1x overlaps CSR chain
  hipEventRecord(e1, stream);
  hipStreamWaitEvent(s2, e1, 0);
  k_scores1x<<<(kN * 64 + 255) / 256, 256, 0, s2>>>(x);
  hipEventRecord(e2, s2);

  // main: CSR build
  k_scanA<<<kScanB, 256, 0, stream>>>();
  k_scanC<<<kScanB, 256, 0, stream>>>();
  k_scatter<<<kHistB, 256, 0, stream>>>(ei);

  // join, then the dependent tail
  hipStreamWaitEvent(stream, e2, 0);
  k_agg1x<<<(kN * 64 + 255) / 256, 256, 0, stream>>>();
  dim3 gf(1, (kN + 63) / 64, 4);
  k_fused<<<gf, 256, 0, stream>>>(b1);
  k_agg2s<<<(kN * 64 + 255) / 256, 256, 0, stream>>>(out);
}

// Round 24
// 334.149 us; speedup vs baseline: 1.0680x; 1.0680x over previous
//
#include <hip/hip_runtime.h>
#include <cstdint>
#include <cstddef>

constexpr int kN   = 50000;          // nodes
constexpr int kE   = 800000;         // edges (without self loops)
constexpr int kEt  = kE + kN;        // edges + self loops
constexpr float kSlope = 0.2f;       // leaky relu slope
constexpr int kScanB = (kN + 255) / 256;       // 196 scan blocks
constexpr int kConvB = (kN * 16 + 255) / 256;  // x-conversion blocks (3125)
constexpr int kHistB = (kEt + 255) / 256;      // hist blocks (3321)

typedef __attribute__((ext_vector_type(8))) short bf8_t;   // 8 bf16 = 4 VGPRs
typedef __attribute__((ext_vector_type(4))) float f4_t;

// ---------------- static device workspace (d_ws unused) ---------------------
__device__ __align__(16) unsigned short g_xb[(size_t)kN * 128];     // x in bf16
__device__ __align__(16) unsigned short g_aggx[(size_t)kN * 512];   // agg of x, bf16
__device__ __align__(16) unsigned short g_w1t[4 * 128 * 128];       // W1^T per head, bf16
__device__ __align__(16) float g_u[3][512];     // W2 @ [a2s, a2d, fcw]
__device__ __align__(16) float g_es1[kN * 4];
__device__ __align__(16) float g_ed1[kN * 4];
__device__ __align__(16) float2 g_sp[kN];       // {es2, phi} packed
__device__ float g_ed2[kN];
__device__ float g_c0;                          // b2 . fcw + fcb
__device__ __align__(16) float g_p1s[4 * 128];  // folded W1_h @ a1_src_h
__device__ __align__(16) float g_p1d[4 * 128];
// CSR by destination:
__device__ int g_deg[kN];   // starts zero (.bss); re-zeroed by k_scanA each call
__device__ int g_ptr[kN + 1];
__device__ int g_cur[kN];
__device__ int g_srcs[kEt];
__device__ int g_bsum[kScanB];

__device__ __forceinline__ float lrelu(float x) { return x > 0.f ? x : kSlope * x; }

__device__ __forceinline__ bf8_t bf8_zero() {
  uint4 z = make_uint4(0u, 0u, 0u, 0u);
  return *(bf8_t*)&z;
}

// round-to-nearest-even f32 -> bf16
__device__ __forceinline__ unsigned short f2bf1(float v) {
  unsigned u = __float_as_uint(v);
  unsigned r = (u + 0x7FFFu + ((u >> 16) & 1u)) >> 16;
  return (unsigned short)r;
}

// -- merged init: zero(sp,ed2) | W1 conv | prep1 | U | c0 | x->bf16 | hist ---
// g_deg is NOT zeroed here: k_scanA zeroes it after consumption each call,
// so it is always zero at entry (module load zero-inits it for call #1).
__global__ __launch_bounds__(256) void k_init(const float* __restrict__ x,
    const int* __restrict__ ei,
    const float* __restrict__ W1, const float* __restrict__ W2,
    const float* __restrict__ a1s, const float* __restrict__ a1d,
    const float* __restrict__ a2s, const float* __restrict__ a2d,
    const float* __restrict__ b2, const float* __restrict__ fcw,
    const float* __restrict__ fcb) {
  const int b = blockIdx.x, t = threadIdx.x;
  if (b < 197) {
    int i = b * 256 + t;
    if (i < kN) {
      g_sp[i] = make_float2(0.f, 0.f);
      g_ed2[i] = 0.f;
    }
  } else if (b < 453) {
    int gid = (b - 197) * 256 + t;   // 0..65535 : W1 -> per-head W1^T bf16
    int h = gid >> 14, rem = gid & 16383;
    int c = rem >> 7, j = rem & 127;
    float v = W1[(size_t)c * 512 + h * 128 + j];
    g_w1t[((size_t)h * 128 + j) * 128 + c] = f2bf1(v);
  } else if (b < 457) {
    int gid = (b - 453) * 256 + t;   // 0..1023 : fold a1 through W1
    int which = gid >> 9, idx = gid & 511;
    int h = idx >> 7, k = idx & 127;
    const float* a = which ? a1d : a1s;
    const float* wrow = W1 + (size_t)k * 512 + h * 128;
    float s = 0.f;
#pragma unroll 8
    for (int c = 0; c < 128; ++c) s += wrow[c] * a[h * 128 + c];
    (which ? g_p1d : g_p1s)[idx] = s;
  } else if (b < 463) {
    int gid = (b - 457) * 256 + t;   // 0..1535 : U[v][k] = W2[k,:] . V_v
    if (gid < 1536) {
      int v = gid >> 9, k = gid & 511;
      const float* vv = v == 0 ? a2s : v == 1 ? a2d : fcw;
      const float* wrow = W2 + (size_t)k * 128;
      float s = 0.f;
#pragma unroll 8
      for (int c = 0; c < 128; ++c) s += wrow[c] * vv[c];
      g_u[v][k] = s;
    }
  } else if (b < 464) {
    if (t < 64) {
      float s = b2[t] * fcw[t] + b2[64 + t] * fcw[64 + t];
#pragma unroll
      for (int off = 32; off > 0; off >>= 1) s += __shfl_down(s, off);
      if (t == 0) g_c0 = s + fcb[0];
    }
  } else if (b < 464 + kConvB) {
    // x -> bf16, 8 elems per thread
    int g = (b - 464) * 256 + t;
    if (g < kN * 16) {
      const float* xp = x + (size_t)g * 8;
      float4 f0 = *(const float4*)xp;
      float4 f1 = *(const float4*)(xp + 4);
      unsigned w0 = (unsigned)f2bf1(f0.x) | ((unsigned)f2bf1(f0.y) << 16);
      unsigned w1 = (unsigned)f2bf1(f0.z) | ((unsigned)f2bf1(f0.w) << 16);
      unsigned w2 = (unsigned)f2bf1(f1.x) | ((unsigned)f2bf1(f1.y) << 16);
      unsigned w3 = (unsigned)f2bf1(f1.z) | ((unsigned)f2bf1(f1.w) << 16);
      *(uint4*)(g_xb + (size_t)g * 8) = make_uint4(w0, w1, w2, w3);
    }
  } else {
    // histogram of destination degrees
    int e = (b - 464 - kConvB) * 256 + t;
    if (e < kEt) {
      int d = (e < kE) ? ei[kE + e] : e - kE;
      atomicAdd(&g_deg[d], 1);
    }
  }
}

// ---- parallel scan, phase A: per-256-chunk LDS scan + block sums -----------
// Also re-zeroes g_deg after reading (invariant: deg==0 at next call's entry).
__global__ __launch_bounds__(256) void k_scanA() {
  __shared__ int s[256];
  const int b = blockIdx.x, t = threadIdx.x;
  const int i = b * 256 + t;
  int d = (i < kN) ? g_deg[i] : 0;
  s[t] = d;
  __syncthreads();
  for (int off = 1; off < 256; off <<= 1) {
    int v = s[t];
    int u = (t >= off) ? s[t - off] : 0;
    __syncthreads();
    s[t] = v + u;
    __syncthreads();
  }
  if (t == 255) g_bsum[b] = s[255];
  if (i < kN) {
    g_ptr[i] = s[t] - d;   // local exclusive
    g_deg[i] = 0;          // restore invariant for next call
  }
}

// ---- phase C (merged B): every block scans bsum in LDS, adds its offset ----
__global__ __launch_bounds__(256) void k_scanC() {
  __shared__ int s[256];
  const int b = blockIdx.x, t = threadIdx.x;
  int v = (t < kScanB) ? g_bsum[t] : 0;
  s[t] = v;
  __syncthreads();
  for (int off = 1; off < 256; off <<= 1) {
    int a = s[t];
    int u = (t >= off) ? s[t - off] : 0;
    __syncthreads();
    s[t] = a + u;
    __syncthreads();
  }
  const int boff = (b > 0) ? s[b - 1] : 0;   // exclusive offset for this block
  __syncthreads();
  const int i = b * 256 + t;
  if (i < kN) {
    int p = g_ptr[i] + boff;
    g_ptr[i] = p;
    g_cur[i] = p;
  }
  if (b == 0 && t == 0) g_ptr[kN] = kEt;
}

__global__ __launch_bounds__(256) void k_scatter(const int* __restrict__ ei) {
  int e = blockIdx.x * 256 + threadIdx.x;
  if (e >= kEt) return;
  int s, d;
  if (e < kE) { s = ei[e]; d = ei[kE + e]; } else { s = d = e - kE; }
  int slot = atomicAdd(&g_cur[d], 1);
  g_srcs[slot] = s;
}

// ---- layer-1 scores directly from x ----
__global__ __launch_bounds__(256) void k_scores1x(const float* __restrict__ x) {
  const int lane = threadIdx.x & 63;
  const int n = (blockIdx.x * 256 + threadIdx.x) >> 6;
  if (n >= kN) return;
  float x0 = x[(size_t)n * 128 + lane];
  float x1 = x[(size_t)n * 128 + 64 + lane];
  float s[4], d[4];
#pragma unroll
  for (int h = 0; h < 4; ++h) {
    s[h] = x0 * g_p1s[h * 128 + lane] + x1 * g_p1s[h * 128 + 64 + lane];
    d[h] = x0 * g_p1d[h * 128 + lane] + x1 * g_p1d[h * 128 + 64 + lane];
  }
#pragma unroll
  for (int off = 32; off > 0; off >>= 1) {
#pragma unroll
    for (int h = 0; h < 4; ++h) {
      s[h] += __shfl_down(s[h], off);
      d[h] += __shfl_down(d[h], off);
    }
  }
  if (lane == 0) {
    *(float4*)(g_es1 + (size_t)n * 4) = make_float4(s[0], s[1], s[2], s[3]);
    *(float4*)(g_ed1 + (size_t)n * 4) = make_float4(d[0], d[1], d[2], d[3]);
  }
}

// ---- layer-1 aggregation: 4 edges/iter (16-lane quarters), bf16 x gathers --
__global__ __launch_bounds__(256) void k_agg1x() {
  const int lane = threadIdx.x & 63;
  const int n = (blockIdx.x * 256 + threadIdx.x) >> 6;
  if (n >= kN) return;
  const int beg = g_ptr[n], end = g_ptr[n + 1];
  const float4 ed = *(const float4*)(g_ed1 + (size_t)n * 4);
  const int qt = lane >> 4, ql = lane & 15;
  float z0 = 0.f, z1 = 0.f, z2 = 0.f, z3 = 0.f;
  float acc[4][8] = {};
  for (int base = beg; base < end; base += 64) {
    const int cnt = min(64, end - base);
    int s = 0;
    float w0 = 0.f, w1 = 0.f, w2 = 0.f, w3 = 0.f;
    if (lane < cnt) {
      s = g_srcs[base + lane];
      float4 es = *(const float4*)(g_es1 + (size_t)s * 4);
      w0 = __expf(lrelu(es.x + ed.x));
      w1 = __expf(lrelu(es.y + ed.y));
      w2 = __expf(lrelu(es.z + ed.z));
      w3 = __expf(lrelu(es.w + ed.w));
      z0 += w0; z1 += w1; z2 += w2; z3 += w3;
    }
    const int quads = (cnt + 3) >> 2;
#pragma unroll 2
    for (int p = 0; p < quads; ++p) {
      int ei = 4 * p + qt;
      int   sj = __shfl(s, ei);
      float b0 = __shfl(w0, ei), b1 = __shfl(w1, ei);
      float b2 = __shfl(w2, ei), b3 = __shfl(w3, ei);
      uint4 uu = *(const uint4*)(g_xb + (size_t)sj * 128 + ql * 8);
      unsigned ww[4] = {uu.x, uu.y, uu.z, uu.w};
      float fv[8];
#pragma unroll
      for (int wdi = 0; wdi < 4; ++wdi) {
        fv[2 * wdi]     = __uint_as_float(ww[wdi] << 16);
        fv[2 * wdi + 1] = __uint_as_float(ww[wdi] & 0xFFFF0000u);
      }
#pragma unroll
      for (int k = 0; k < 8; ++k) {
        acc[0][k] += b0 * fv[k];
        acc[1][k] += b1 * fv[k];
        acc[2][k] += b2 * fv[k];
        acc[3][k] += b3 * fv[k];
      }
    }
  }
#pragma unroll
  for (int h = 0; h < 4; ++h)
#pragma unroll
    for (int k = 0; k < 8; ++k) {
      acc[h][k] += __shfl_xor(acc[h][k], 16);
      acc[h][k] += __shfl_xor(acc[h][k], 32);
    }
#pragma unroll
  for (int off = 1; off < 64; off <<= 1) {
    z0 += __shfl_xor(z0, off); z1 += __shfl_xor(z1, off);
    z2 += __shfl_xor(z2, off); z3 += __shfl_xor(z3, off);
  }
  float zh = qt == 0 ? z0 : qt == 1 ? z1 : qt == 2 ? z2 : z3;
  float iz = 1.f / zh;
  ushort4 o0, o1;
  float v[8];
#pragma unroll
  for (int k = 0; k < 8; ++k)
    v[k] = (qt == 0 ? acc[0][k] : qt == 1 ? acc[1][k] : qt == 2 ? acc[2][k] : acc[3][k]) * iz;
  o0.x = f2bf1(v[0]); o0.y = f2bf1(v[1]); o0.z = f2bf1(v[2]); o0.w = f2bf1(v[3]);
  o1.x = f2bf1(v[4]); o1.y = f2bf1(v[5]); o1.z = f2bf1(v[6]); o1.w = f2bf1(v[7]);
  size_t o = (size_t)n * 512 + qt * 128 + ql * 8;
  *(ushort4*)(g_aggx + o)     = o0;
  *(ushort4*)(g_aggx + o + 4) = o1;
}

// ------- fused layer-1 expand + layer-2 projections, head-split -------------
__global__ __launch_bounds__(256) void k_fused(const float* __restrict__ b1) {
  __shared__ float sred[2][64][3];
  const int t = threadIdx.x;
  const int lane = t & 63, w = t >> 6;
  const int wrow = w >> 1, wcol = w & 1;
  const int ln15 = lane & 15, q = lane >> 4, qo = q * 8;
  const int row0 = blockIdx.y * 64;
  const int h = blockIdx.z;

  float part[2][4][3] = {};      // [i][reg][v]
  f4_t h1acc[2][4] = {};
#pragma unroll
  for (int ks = 0; ks < 128; ks += 32) {
    bf8_t ah[2];
#pragma unroll
    for (int i = 0; i < 2; ++i) {
      int r = row0 + wrow * 32 + i * 16 + ln15;
      ah[i] = bf8_zero();
      if (r < kN)
        ah[i] = *(const bf8_t*)&g_aggx[(size_t)r * 512 + h * 128 + ks + qo];
    }
#pragma unroll
    for (int j = 0; j < 4; ++j) {
      size_t gb = ((size_t)h * 128 + wcol * 64 + j * 16 + ln15) * 128 + ks + qo;
      bf8_t bh = *(const bf8_t*)&g_w1t[gb];
#pragma unroll
      for (int i = 0; i < 2; ++i)
        h1acc[i][j] = __builtin_amdgcn_mfma_f32_16x16x32_bf16(ah[i], bh, h1acc[i][j], 0, 0, 0);
    }
  }
  // epilogue: relu(h1+b1) dotted with U columns
#pragma unroll
  for (int j = 0; j < 4; ++j) {
    int col = h * 128 + wcol * 64 + j * 16 + ln15;
    float bv = b1[col];
    float u0 = g_u[0][col], u1 = g_u[1][col], u2 = g_u[2][col];
#pragma unroll
    for (int i = 0; i < 2; ++i)
#pragma unroll
      for (int reg = 0; reg < 4; ++reg) {
        float v = fmaxf(h1acc[i][j][reg] + bv, 0.f);
        part[i][reg][0] += v * u0;
        part[i][reg][1] += v * u1;
        part[i][reg][2] += v * u2;
      }
  }
  // reduce over the 16 lanes of each quad-group (same q)
#pragma unroll
  for (int off = 1; off < 16; off <<= 1)
#pragma unroll
    for (int i = 0; i < 2; ++i)
#pragma unroll
      for (int reg = 0; reg < 4; ++reg)
#pragma unroll
        for (int v = 0; v < 3; ++v)
          part[i][reg][v] += __shfl_xor(part[i][reg][v], off);
  if (ln15 == 0) {
#pragma unroll
    for (int i = 0; i < 2; ++i)
#pragma unroll
      for (int reg = 0; reg < 4; ++reg) {
        int rl = wrow * 32 + i * 16 + q * 4 + reg;
#pragma unroll
        for (int v = 0; v < 3; ++v) sred[wcol][rl][v] = part[i][reg][v];
      }
  }
  __syncthreads();
  if (t < 192) {
    int row = t / 3, v = t - row * 3;
    float s = sred[0][row][v] + sred[1][row][v];
    int r = row0 + row;
    if (r < kN) {
      float* dst = v == 0 ? &g_sp[r].x : v == 1 ? &g_ed2[r] : &g_sp[r].y;
      atomicAdd(dst, s);
    }
  }
}

// ---- layer-2 scalar aggregation + output: out = (sum w*phi)/z + c0 ---------
__global__ __launch_bounds__(256) void k_agg2s(float* __restrict__ out) {
  const int lane = threadIdx.x & 63;
  const int n = (blockIdx.x * 256 + threadIdx.x) >> 6;
  if (n >= kN) return;
  const int beg = g_ptr[n], end = g_ptr[n + 1];
  const float ed = g_ed2[n];
  float zp = 0.f, num = 0.f;
  for (int base = beg; base < end; base += 64) {
    int slot = base + lane;
    if (slot < end) {
      int s = g_srcs[slot];
      float2 sp = g_sp[s];
      float w = __expf(lrelu(sp.x + ed));
      zp += w;
      num += w * sp.y;
    }
  }
#pragma unroll
  for (int off = 1; off < 64; off <<= 1) {
    zp  += __shfl_xor(zp, off);
    num += __shfl_xor(num, off);
  }
  if (lane == 0) out[n] = num / zp + g_c0;
}

extern "C" void kernel_launch(void* const* d_in, const int* in_sizes, int n_in,
                              void* d_out, int out_size, void* d_ws, size_t ws_size,
                              hipStream_t stream) {
  const float* x   = (const float*)d_in[0];
  const int*   ei  = (const int*)d_in[1];
  const float* W1  = (const float*)d_in[2];
  const float* a1s = (const float*)d_in[3];
  const float* a1d = (const float*)d_in[4];
  const float* b1  = (const float*)d_in[5];
  const float* W2  = (const float*)d_in[6];
  const float* a2s = (const float*)d_in[7];
  const float* a2d = (const float*)d_in[8];
  const float* b2  = (const float*)d_in[9];
  const float* fcw = (const float*)d_in[10];
  const float* fcb = (const float*)d_in[11];
  float* out = (float*)d_out;
  (void)d_ws; (void)ws_size; (void)in_sizes; (void)n_in; (void)out_size;

  // ---- init (zero | W1 conv | prep1 | U | c0 | x->bf16 | hist) ----
  k_init<<<464 + kConvB + kHistB, 256, 0, stream>>>(x, ei, W1, W2, a1s, a1d,
                                                    a2s, a2d, b2, fcw, fcb);
  // ---- CSR build ----
  k_scanA<<<kScanB, 256, 0, stream>>>();
  k_scanC<<<kScanB, 256, 0, stream>>>();
  k_scatter<<<kHistB, 256, 0, stream>>>(ei);

  // ---- layer 1 ----
  k_scores1x<<<(kN * 64 + 255) / 256, 256, 0, stream>>>(x);
  k_agg1x<<<(kN * 64 + 255) / 256, 256, 0, stream>>>();

  // ---- fused expand + layer-2 projections (head-split, atomic combine) ----
  dim3 gf(1, (kN + 63) / 64, 4);
  k_fused<<<gf, 256, 0, stream>>>(b1);

  // ---- layer-2 scalar edge aggregation + output ----
  k_agg2s<<<(kN * 64 + 255) / 256, 256, 0, stream>>>(out);
}